// Round 7
// baseline (42.900 us; speedup 1.0000x reference)
//
#include <hip/hip_runtime.h>
#include <hip/hip_bf16.h>

// Problem constants: B=1, N=1024, T=2048, E=16384, K=32.
#define TT  2048
#define KK  32
#define NN  1024
#define EE  16384
#define CAP 64   // per-row expert cap (Poisson(16); P(>64) ~ 1e-21)

typedef short short8 __attribute__((ext_vector_type(8)));
typedef float f32x4 __attribute__((ext_vector_type(4)));

__device__ __forceinline__ short f2bf(float f) {
    __hip_bfloat16 h = __float2bfloat16(f);
    return __builtin_bit_cast(short, h);
}

// Single fused kernel. One block per row n; 4 independent waves own 512-wide
// t-slices (plain stores, no atomics, no barriers after the 2 scan barriers).
// Verified MFMA math (R2-R5): per 256-output segment s of the slice,
//   A1 b128 at xs[256s+16c+8g], A2 at +16   (xs = [32 halo | 512 slice] bf16)
//   b1 = kt[a][s1..+8), b2 = kt[a][s1+16..+24) with g<2 -> 0 (REQUIRED)
//   kt[a][((a+1)&7)+47-m] = tap[m];  a=c&7, s1=((a+1)&7)+15-c+8g (8-aligned)
//   D: col=c=lane&15, row=4g+q -> t = 512w + 256s + 64g + 16q + c
__global__ __launch_bounds__(256, 4) void lti_kernel(
    const float* __restrict__ x,     // [N, T]
    const float* __restrict__ kern,  // [E, K]
    const int*   __restrict__ src,   // [E]
    const int*   __restrict__ dst,   // [E]
    float*       __restrict__ out)   // [N, T]
{
    const int n   = blockIdx.x;
    const int tid = threadIdx.x;
    const int w   = tid >> 6;        // t-slice 0..3
    const int ln  = tid & 63;
    const int c   = ln & 15, g = ln >> 4;
    const int t0  = 512 * w;

    __shared__ __align__(16) short xs_all[4][544];    // per-wave [32 halo | 512 slice]
    __shared__ __align__(16) short kt_all[4][8][72];  // per-wave shifted taps table
    __shared__ int bl[CAP];
    __shared__ int bc;

    short* xs = xs_all[w];
    short (*kt)[72] = kt_all[w];

    short8 z8; z8[0]=0;z8[1]=0;z8[2]=0;z8[3]=0;z8[4]=0;z8[5]=0;z8[6]=0;z8[7]=0;

    if (tid == 0) bc = 0;
    {   // per-wave init: zero taps table; wave 0 zeroes its causal halo (persists)
        short8* kz = (short8*)&kt[0][0];   // 576 shorts = 72 short8
        kz[ln] = z8;
        if (ln < 8) kz[64 + ln] = z8;
        if (w == 0 && ln < 4) *(short8*)&xs[8 * ln] = z8;
    }
    __syncthreads();

    // Block-coop dst scan -> expert list for row n (16 int4 iters, all in flight).
    const int4* d4 = (const int4*)dst;
    #pragma unroll
    for (int it = 0; it < EE / 1024; ++it) {
        const int i4 = tid + 256 * it;
        const int4 d = d4[i4];
        const int eb = 4 * i4;
        if (d.x == n) { int p = atomicAdd(&bc, 1); if (p < CAP) bl[p] = (src[eb    ] << 14) | (eb    ); }
        if (d.y == n) { int p = atomicAdd(&bc, 1); if (p < CAP) bl[p] = (src[eb + 1] << 14) | (eb + 1); }
        if (d.z == n) { int p = atomicAdd(&bc, 1); if (p < CAP) bl[p] = (src[eb + 2] << 14) | (eb + 2); }
        if (d.w == n) { int p = atomicAdd(&bc, 1); if (p < CAP) bl[p] = (src[eb + 3] << 14) | (eb + 3); }
    }
    __syncthreads();
    int L = bc; if (L > CAP) L = CAP;

    f32x4 acc0 = {0,0,0,0}, acc1 = {0,0,0,0};
    short8 rowA, rowB, haloA = z8, haloB = z8;
    float4 tapA = {0,0,0,0}, tapB = {0,0,0,0};

    // ---- pipeline stages (named reg-sets A/B; rule #20: no runtime indexing) ----
    #define LOAD_EX(S, SV)                                                             \
    {                                                                                  \
        const int e0 = __builtin_amdgcn_readfirstlane((int)((SV) & 16383u));           \
        const int s0 = __builtin_amdgcn_readfirstlane((int)((SV) >> 14));              \
        const float4* xr = (const float4*)(x + (size_t)s0 * TT + t0);                  \
        float4 u = xr[2 * ln], v = xr[2 * ln + 1];                                     \
        row##S[0]=f2bf(u.x); row##S[1]=f2bf(u.y); row##S[2]=f2bf(u.z); row##S[3]=f2bf(u.w); \
        row##S[4]=f2bf(v.x); row##S[5]=f2bf(v.y); row##S[6]=f2bf(v.z); row##S[7]=f2bf(v.w); \
        if (w && ln < 4) {                                                             \
            u = *(const float4*)(x + (size_t)s0 * TT + t0 - 32 + 8 * ln);              \
            v = *(const float4*)(x + (size_t)s0 * TT + t0 - 28 + 8 * ln);              \
            halo##S[0]=f2bf(u.x); halo##S[1]=f2bf(u.y); halo##S[2]=f2bf(u.z); halo##S[3]=f2bf(u.w); \
            halo##S[4]=f2bf(v.x); halo##S[5]=f2bf(v.y); halo##S[6]=f2bf(v.z); halo##S[7]=f2bf(v.w); \
        }                                                                              \
        tap##S = *(const float4*)(kern + (size_t)e0 * KK + 4 * (ln & 7));              \
    }

    #define COMMIT_EX(S)                                                               \
    {                                                                                  \
        *(short8*)&xs[32 + 8 * ln] = row##S;                                           \
        if (w && ln < 4) *(short8*)&xs[8 * ln] = halo##S;                              \
        {   /* 64-lane tap scatter: copy a2 = ln>>3, taps mb..mb+3 = 4*(ln&7).. */     \
            const int a2  = ln >> 3;                                                   \
            const int pad = (a2 + 1) & 7;                                              \
            const int mb  = 4 * (ln & 7);                                              \
            kt[a2][pad + 47 - mb]     = f2bf(tap##S.x);                                \
            kt[a2][pad + 46 - mb]     = f2bf(tap##S.y);                                \
            kt[a2][pad + 45 - mb]     = f2bf(tap##S.z);                                \
            kt[a2][pad + 44 - mb]     = f2bf(tap##S.w);                                \
        }                                                                              \
    }

    const int a_ = c & 7;
    const int s1 = ((a_ + 1) & 7) + 15 - c + 8 * g;   // b128-aligned by construction

    #define COMPUTE()                                                                  \
    {                                                                                  \
        const short8 b1 = *(const short8*)&kt[a_][s1];                                 \
        short8 b2 = *(const short8*)&kt[a_][s1 + 16];                                  \
        if (g < 2) b2 = z8;   /* k<16 zeroing is REQUIRED */                           \
        {                                                                              \
            const short8 a1  = *(const short8*)&xs[16 * c + 8 * g];                    \
            const short8 a2v = *(const short8*)&xs[16 * c + 8 * g + 16];               \
            acc0 = __builtin_amdgcn_mfma_f32_16x16x32_bf16(a1,  b1, acc0, 0, 0, 0);    \
            acc0 = __builtin_amdgcn_mfma_f32_16x16x32_bf16(a2v, b2, acc0, 0, 0, 0);    \
        }                                                                              \
        {                                                                              \
            const short8 a1  = *(const short8*)&xs[256 + 16 * c + 8 * g];              \
            const short8 a2v = *(const short8*)&xs[256 + 16 * c + 8 * g + 16];         \
            acc1 = __builtin_amdgcn_mfma_f32_16x16x32_bf16(a1,  b1, acc1, 0, 0, 0);    \
            acc1 = __builtin_amdgcn_mfma_f32_16x16x32_bf16(a2v, b2, acc1, 0, 0, 0);    \
        }                                                                              \
    }

    if (L > 0) {
        // Prologue: e0 staged; e1 in regs; slot(2) prefetched.
        unsigned svA = (unsigned)bl[0];
        LOAD_EX(A, svA);
        COMMIT_EX(A);
        if (L > 1) { unsigned svB = (unsigned)bl[1]; LOAD_EX(B, svB); }
        svA = (L > 2) ? (unsigned)bl[2] : 0u;

        // Invariant at p: xs = e_p, rowB = e_{p+1}, svA = slot(p+2).
        for (int p = 0; p < L; p += 2) {
            const unsigned svC = (p + 3 < L) ? (unsigned)bl[p + 3] : 0u;
            COMPUTE();                             // expert p
            if (p + 2 < L) LOAD_EX(A, svA);        // e_{p+2} global loads in flight
            if (p + 1 < L) { COMMIT_EX(B); COMPUTE(); }   // expert p+1
            if (p + 4 < L) svA = (unsigned)bl[p + 4];
            if (p + 3 < L) LOAD_EX(B, svC);        // e_{p+3} in flight across iter
            if (p + 2 < L) COMMIT_EX(A);           // xs = e_{p+2}
        }
    }

    // Epilogue: wave owns out[n, t0..t0+512) exclusively -> plain stores (always
    // executed: full overwrite of poisoned d_out, acc==0 when L==0).
    const float* xr  = x   + (size_t)n * TT + t0;
    float*       orw = out + (size_t)n * TT + t0;
    #pragma unroll
    for (int q = 0; q < 4; ++q) {
        const int ta = 64 * g + 16 * q + c;
        orw[ta]       = xr[ta]       + acc0[q];
        orw[256 + ta] = xr[256 + ta] + acc1[q];
    }
    #undef LOAD_EX
    #undef COMMIT_EX
    #undef COMPUTE
}

extern "C" void kernel_launch(void* const* d_in, const int* in_sizes, int n_in,
                              void* d_out, int out_size, void* d_ws, size_t ws_size,
                              hipStream_t stream) {
    const float* x    = (const float*)d_in[0];
    const float* kern = (const float*)d_in[1];
    const int*   src  = (const int*)d_in[2];
    const int*   dst  = (const int*)d_in[3];
    float*       out  = (float*)d_out;

    lti_kernel<<<dim3(NN), dim3(256), 0, stream>>>(x, kern, src, dst, out);
}

// Round 8
// 41.047 us; speedup vs baseline: 1.0451x; 1.0451x over previous
//
#include <hip/hip_runtime.h>
#include <hip/hip_bf16.h>

// Problem constants: B=1, N=1024, T=2048, E=16384, K=32.
#define TT  2048
#define KK  32
#define NN  1024
#define EE  16384
#define CAP 64   // per-row expert cap (Poisson(16); P(>64) ~ 1e-21)

typedef short short8 __attribute__((ext_vector_type(8)));
typedef float f32x4 __attribute__((ext_vector_type(4)));

__device__ __forceinline__ short f2bf(float f) {
    __hip_bfloat16 h = __float2bfloat16(f);
    return __builtin_bit_cast(short, h);
}

// One block per row n, 512 threads = 8 waves. Wave v = (slice w = v&3, parity q = v>>2).
// Wave processes experts p = q, q+2, ... of the row over its 512-wide t-slice.
// Slice outputs are combined across the two parity waves via an LDS reduction
// buffer (one end barrier), then stored with plain coalesced stores. No atomics.
// Verified MFMA math (R2-R6): per 256-output segment s of the slice,
//   A1 b128 at xs[256s+16c+8g], A2 at +16   (xs = [32 halo | 512 slice] bf16)
//   b1 = kt[a][s1..+8), b2 = kt[a][s1+16..+24) with g<2 -> 0 (REQUIRED)
//   kt[a][((a+1)&7)+47-m] = tap[m];  a=c&7, s1=((a+1)&7)+15-c+8g (8-aligned)
//   D: col=c=lane&15, row=4g+qd -> t = 512w + 256s + 64g + 16qd + c
__global__ __launch_bounds__(512, 8) void lti_kernel(
    const float* __restrict__ x,     // [N, T]
    const float* __restrict__ kern,  // [E, K]
    const int*   __restrict__ src,   // [E]
    const int*   __restrict__ dst,   // [E]
    float*       __restrict__ out)   // [N, T]
{
    const int n   = blockIdx.x;
    const int tid = threadIdx.x;
    const int v   = tid >> 6;        // wave 0..7
    const int w   = v & 3;           // t-slice 0..3
    const int q   = v >> 2;          // expert parity 0..1
    const int ln  = tid & 63;
    const int c   = ln & 15, g = ln >> 4;
    const int t0  = 512 * w;

    __shared__ __align__(16) short xs_all[8][544];    // per-wave [32 halo | 512 slice]
    __shared__ __align__(16) short kt_all[8][8][72];  // per-wave shifted taps table
    __shared__ __align__(16) float red[4][512];       // per-slice parity-1 partials
    __shared__ int bl[CAP];
    __shared__ int bc;

    short* xs = xs_all[v];
    short (*kt)[72] = kt_all[v];

    short8 z8; z8[0]=0;z8[1]=0;z8[2]=0;z8[3]=0;z8[4]=0;z8[5]=0;z8[6]=0;z8[7]=0;

    if (tid == 0) bc = 0;
    {   // per-wave init: zero taps table; w==0 waves zero their causal halo (persists)
        short8* kz = (short8*)&kt[0][0];   // 576 shorts = 72 short8
        kz[ln] = z8;
        if (ln < 8) kz[64 + ln] = z8;
        if (w == 0 && ln < 4) *(short8*)&xs[8 * ln] = z8;
    }
    __syncthreads();

    // Block-coop dst scan -> expert list for row n (8 int4 iters, all in flight).
    const int4* d4 = (const int4*)dst;
    #pragma unroll
    for (int it = 0; it < EE / 2048; ++it) {
        const int i4 = tid + 512 * it;
        const int4 d = d4[i4];
        const int eb = 4 * i4;
        if (d.x == n) { int p = atomicAdd(&bc, 1); if (p < CAP) bl[p] = (src[eb    ] << 14) | (eb    ); }
        if (d.y == n) { int p = atomicAdd(&bc, 1); if (p < CAP) bl[p] = (src[eb + 1] << 14) | (eb + 1); }
        if (d.z == n) { int p = atomicAdd(&bc, 1); if (p < CAP) bl[p] = (src[eb + 2] << 14) | (eb + 2); }
        if (d.w == n) { int p = atomicAdd(&bc, 1); if (p < CAP) bl[p] = (src[eb + 3] << 14) | (eb + 3); }
    }
    __syncthreads();
    int L = bc; if (L > CAP) L = CAP;
    // This wave's expert subset: p = q + 2*i, i in [0, M).
    const int M = (L - q + 1) >> 1;
    #define IDX(I) (q + 2 * (I))

    f32x4 acc0 = {0,0,0,0}, acc1 = {0,0,0,0};
    short8 rowA, rowB, haloA = z8, haloB = z8;
    float4 tapA = {0,0,0,0}, tapB = {0,0,0,0};

    // ---- pipeline stages (named reg-sets A/B; rule #20: no runtime indexing) ----
    #define LOAD_EX(S, SV)                                                             \
    {                                                                                  \
        const int e0 = __builtin_amdgcn_readfirstlane((int)((SV) & 16383u));           \
        const int s0 = __builtin_amdgcn_readfirstlane((int)((SV) >> 14));              \
        const float4* xr = (const float4*)(x + (size_t)s0 * TT + t0);                  \
        float4 u = xr[2 * ln], vv = xr[2 * ln + 1];                                    \
        row##S[0]=f2bf(u.x); row##S[1]=f2bf(u.y); row##S[2]=f2bf(u.z); row##S[3]=f2bf(u.w); \
        row##S[4]=f2bf(vv.x); row##S[5]=f2bf(vv.y); row##S[6]=f2bf(vv.z); row##S[7]=f2bf(vv.w); \
        if (w && ln < 4) {                                                             \
            u  = *(const float4*)(x + (size_t)s0 * TT + t0 - 32 + 8 * ln);             \
            vv = *(const float4*)(x + (size_t)s0 * TT + t0 - 28 + 8 * ln);             \
            halo##S[0]=f2bf(u.x); halo##S[1]=f2bf(u.y); halo##S[2]=f2bf(u.z); halo##S[3]=f2bf(u.w); \
            halo##S[4]=f2bf(vv.x); halo##S[5]=f2bf(vv.y); halo##S[6]=f2bf(vv.z); halo##S[7]=f2bf(vv.w); \
        }                                                                              \
        tap##S = *(const float4*)(kern + (size_t)e0 * KK + 4 * (ln & 7));              \
    }

    #define COMMIT_EX(S)                                                               \
    {                                                                                  \
        *(short8*)&xs[32 + 8 * ln] = row##S;                                           \
        if (w && ln < 4) *(short8*)&xs[8 * ln] = halo##S;                              \
        {   /* 64-lane tap scatter: table a2 = ln>>3, taps 4*(ln&7).. */               \
            const int a2  = ln >> 3;                                                   \
            const int pad = (a2 + 1) & 7;                                              \
            const int mb  = 4 * (ln & 7);                                              \
            kt[a2][pad + 47 - mb] = f2bf(tap##S.x);                                    \
            kt[a2][pad + 46 - mb] = f2bf(tap##S.y);                                    \
            kt[a2][pad + 45 - mb] = f2bf(tap##S.z);                                    \
            kt[a2][pad + 44 - mb] = f2bf(tap##S.w);                                    \
        }                                                                              \
    }

    const int a_ = c & 7;
    const int s1 = ((a_ + 1) & 7) + 15 - c + 8 * g;   // b128-aligned by construction

    #define COMPUTE()                                                                  \
    {                                                                                  \
        const short8 b1 = *(const short8*)&kt[a_][s1];                                 \
        short8 b2 = *(const short8*)&kt[a_][s1 + 16];                                  \
        if (g < 2) b2 = z8;   /* k<16 zeroing is REQUIRED */                           \
        {                                                                              \
            const short8 a1  = *(const short8*)&xs[16 * c + 8 * g];                    \
            const short8 a2v = *(const short8*)&xs[16 * c + 8 * g + 16];               \
            acc0 = __builtin_amdgcn_mfma_f32_16x16x32_bf16(a1,  b1, acc0, 0, 0, 0);    \
            acc0 = __builtin_amdgcn_mfma_f32_16x16x32_bf16(a2v, b2, acc0, 0, 0, 0);    \
        }                                                                              \
        {                                                                              \
            const short8 a1  = *(const short8*)&xs[256 + 16 * c + 8 * g];              \
            const short8 a2v = *(const short8*)&xs[256 + 16 * c + 8 * g + 16];         \
            acc1 = __builtin_amdgcn_mfma_f32_16x16x32_bf16(a1,  b1, acc1, 0, 0, 0);    \
            acc1 = __builtin_amdgcn_mfma_f32_16x16x32_bf16(a2v, b2, acc1, 0, 0, 0);    \
        }                                                                              \
    }

    if (M > 0) {
        // Prologue: e(idx 0) staged; e(idx 1) in regs; slot(idx 2) prefetched.
        unsigned svA = (unsigned)bl[IDX(0)];
        LOAD_EX(A, svA);
        COMMIT_EX(A);
        if (M > 1) { unsigned svB = (unsigned)bl[IDX(1)]; LOAD_EX(B, svB); }
        svA = (M > 2) ? (unsigned)bl[IDX(2)] : 0u;

        // Invariant at i: xs = e_i, rowB = e_{i+1}, svA = slot(i+2).
        for (int i = 0; i < M; i += 2) {
            const unsigned svC = (i + 3 < M) ? (unsigned)bl[IDX(i + 3)] : 0u;
            COMPUTE();                             // expert idx(i)
            if (i + 2 < M) LOAD_EX(A, svA);        // e_{i+2} global loads in flight
            if (i + 1 < M) { COMMIT_EX(B); COMPUTE(); }   // expert idx(i+1)
            if (i + 4 < M) svA = (unsigned)bl[IDX(i + 4)];
            if (i + 3 < M) LOAD_EX(B, svC);        // e_{i+3} in flight across iter
            if (i + 2 < M) COMMIT_EX(A);           // xs = e_{i+2}
        }
    }

    // Parity-1 waves publish partials; parity-0 waves combine and store.
    if (q == 1) {
        float* rd = &red[w][0];
        #pragma unroll
        for (int qd = 0; qd < 4; ++qd) {
            const int ta = 64 * g + 16 * qd + c;
            rd[ta]       = acc0[qd];
            rd[256 + ta] = acc1[qd];
        }
    }
    __syncthreads();
    if (q == 0) {
        const float* rd  = &red[w][0];
        const float* xr  = x   + (size_t)n * TT + t0;
        float*       orw = out + (size_t)n * TT + t0;
        #pragma unroll
        for (int qd = 0; qd < 4; ++qd) {
            const int ta = 64 * g + 16 * qd + c;
            orw[ta]       = xr[ta]       + acc0[qd] + rd[ta];
            orw[256 + ta] = xr[256 + ta] + acc1[qd] + rd[256 + ta];
        }
    }
    #undef IDX
    #undef LOAD_EX
    #undef COMMIT_EX
    #undef COMPUTE
}

extern "C" void kernel_launch(void* const* d_in, const int* in_sizes, int n_in,
                              void* d_out, int out_size, void* d_ws, size_t ws_size,
                              hipStream_t stream) {
    const float* x    = (const float*)d_in[0];
    const float* kern = (const float*)d_in[1];
    const int*   src  = (const int*)d_in[2];
    const int*   dst  = (const int*)d_in[3];
    float*       out  = (float*)d_out;

    lti_kernel<<<dim3(NN), dim3(512), 0, stream>>>(x, kern, src, dst, out);
}